// Round 1
// baseline (722.547 us; speedup 1.0000x reference)
//
#include <hip/hip_runtime.h>

// Problem constants (from reference): T=1024, B=32, D=768, L=48
#define T_ 1024
#define B_ 32
#define D_ 768
#define L_ 48
#define TB_ (T_ * B_)   // 32768 rows of the emissions GEMM

// ---------------------------------------------------------------------------
// Kernel A: emissions = feats @ W + b   (fp32, M=32768 N=48 K=768)
// block = 256 threads, tile = 128 rows x 48 cols, K-chunks of 64.
// Thread microtile = 4 rows x 6 cols (24 accumulators).
// LDS: feats chunk 128x64 (pad 68) + W chunk transposed 48x64 (pad 68) ~48 KB.
// ---------------------------------------------------------------------------
__global__ __launch_bounds__(256) void emis_gemm(
    const float* __restrict__ feats, const float* __restrict__ W,
    const float* __restrict__ bias, float* __restrict__ em) {
  __shared__ float fbuf[128 * 68];
  __shared__ float wbuf[48 * 68];
  const int tid = threadIdx.x;
  const int cg = tid & 7;    // col group 0..7  -> cols c0..c0+5
  const int rg = tid >> 3;   // row group 0..31 -> rows r0..r0+3
  const int c0 = cg * 6;
  const int r0 = rg * 4;
  const int rowbase = blockIdx.x * 128;

  float acc[4][6];
#pragma unroll
  for (int i = 0; i < 4; i++)
#pragma unroll
    for (int c = 0; c < 6; c++) acc[i][c] = 0.f;

  for (int kc = 0; kc < D_; kc += 64) {
    __syncthreads();  // protect previous chunk's reads
    // stage W chunk transposed: wbuf[j][ko] = W[kc+ko][j]
    for (int i = tid; i < 64 * 48; i += 256) {
      int ko = i / 48;
      int j = i - ko * 48;
      wbuf[j * 68 + ko] = W[(kc + ko) * L_ + j];
    }
    // stage feats chunk: fbuf[r][kp], float4 coalesced
#pragma unroll
    for (int i = 0; i < 8; i++) {
      int flat = i * 1024 + tid * 4;   // 0..8191
      int r = flat >> 6;
      int kp = flat & 63;
      const float4 v =
          *(const float4*)(feats + (size_t)(rowbase + r) * D_ + kc + kp);
      *(float4*)(fbuf + r * 68 + kp) = v;
    }
    __syncthreads();
#pragma unroll
    for (int k4 = 0; k4 < 16; k4++) {
      float4 fv[4];
      float4 wv[6];
#pragma unroll
      for (int i = 0; i < 4; i++)
        fv[i] = *(const float4*)(fbuf + (r0 + i) * 68 + k4 * 4);
#pragma unroll
      for (int c = 0; c < 6; c++)
        wv[c] = *(const float4*)(wbuf + (c0 + c) * 68 + k4 * 4);
#pragma unroll
      for (int i = 0; i < 4; i++) {
#pragma unroll
        for (int c = 0; c < 6; c++) {
          acc[i][c] = fmaf(fv[i].x, wv[c].x, acc[i][c]);
          acc[i][c] = fmaf(fv[i].y, wv[c].y, acc[i][c]);
          acc[i][c] = fmaf(fv[i].z, wv[c].z, acc[i][c]);
          acc[i][c] = fmaf(fv[i].w, wv[c].w, acc[i][c]);
        }
      }
    }
  }
#pragma unroll
  for (int i = 0; i < 4; i++)
#pragma unroll
    for (int c = 0; c < 6; c++)
      em[(size_t)(rowbase + r0 + i) * L_ + c0 + c] = acc[i][c] + bias[c0 + c];
}

// ---------------------------------------------------------------------------
// Kernel B: CRF forward scans in scaled probability space.
// grid = 64 blocks (2 passes x 32 batches), block = 1 wave (64 threads).
// Lane j holds state a[j]; P row (exp of transitions, masked for pass 1)
// lives in 48 VGPRs. Per step: all-gather a via LDS (12 x ds_read_b128
// broadcast), 48 fma matvec, multiply by exp(em), mask, rescale by wave-max
// every 8 steps accumulating log(m).
// ---------------------------------------------------------------------------
__global__ __launch_bounds__(64) void crf_scan(
    const float* __restrict__ em, const int* __restrict__ tags,
    const int* __restrict__ lens, const float* __restrict__ begin,
    const float* __restrict__ trans, const float* __restrict__ endt,
    const int* __restrict__ bc, const int* __restrict__ ec,
    const int* __restrict__ tc, float* __restrict__ out) {
  const int s = blockIdx.x;
  const int pass = s & 1;   // 0 = unconstrained fwd, 1 = constrained partial
  const int b = s >> 1;
  const int lane = threadIdx.x;
  const bool act = lane < L_;
  const int len = lens[b];  // in [512, 1024]

  __shared__ float buf[2][64];

  // Preload transition row: P[k] = exp(trans[lane][k]) (0 where constrained)
  float P[L_];
#pragma unroll
  for (int k = 0; k < L_; k++) P[k] = 0.f;
  if (act) {
#pragma unroll
    for (int k = 0; k < L_; k++) {
      float p = __expf(trans[lane * L_ + k]);
      if (pass && tc[lane * L_ + k]) p = 0.f;
      P[k] = p;
    }
  }

  // Clamped base so inactive lanes load in-bounds (values unused)
  const int base = b * L_ + (act ? lane : 0);

  // init state a0 = exp(em0 + begin), masked
  float a = 0.f;
  if (act) {
    a = __expf(em[base] + begin[lane]);
    if (pass) {
      if (bc[lane]) a = 0.f;
      if (tags[base]) a = 0.f;
    }
  }

  float logacc = 0.f;
  float* cur = &buf[0][0];
  float* nxt = &buf[1][0];
  cur[lane] = act ? a : 0.f;
  __syncthreads();

  // emission/tag prefetch, distance 2 (len >= 512 so t=1,2 exist)
  float em_c = em[1 * (B_ * L_) + base];
  int t2 = (2 < len) ? 2 : (len - 1);
  float em_n = em[t2 * (B_ * L_) + base];
  int tg_c = 0, tg_n = 0;
  if (pass) {
    tg_c = tags[1 * (B_ * L_) + base];
    tg_n = tags[t2 * (B_ * L_) + base];
  }

  for (int t = 1; t < len; ++t) {
    // issue prefetch for t+2
    const int tn = (t + 2 < len) ? (t + 2) : (len - 1);
    const float em_p = em[tn * (B_ * L_) + base];
    int tg_p = 0;
    if (pass) tg_p = tags[tn * (B_ * L_) + base];

    // gather prev state (broadcast reads) + matvec with 4 partial sums
    float s0 = 0.f, s1 = 0.f, s2 = 0.f, s3 = 0.f;
    const float4* c4 = (const float4*)cur;
#pragma unroll
    for (int q = 0; q < 12; q++) {
      const float4 v = c4[q];
      s0 = fmaf(v.x, P[4 * q + 0], s0);
      s1 = fmaf(v.y, P[4 * q + 1], s1);
      s2 = fmaf(v.z, P[4 * q + 2], s2);
      s3 = fmaf(v.w, P[4 * q + 3], s3);
    }
    float u = ((s0 + s1) + (s2 + s3)) * __expf(em_c);
    if (!act || (pass && tg_c)) u = 0.f;

    // rescale every 8 steps (worst-case growth ~800^8 ~ 2e23 << fp32 max)
    if ((t & 7) == 0) {
      float m = u;
#pragma unroll
      for (int off = 32; off; off >>= 1) m = fmaxf(m, __shfl_xor(m, off, 64));
      m = fmaxf(m, 1e-35f);
      u = u / m;
      logacc += __logf(m);
    }

    nxt[lane] = u;
    __syncthreads();
    float* tmp = cur; cur = nxt; nxt = tmp;
    em_c = em_n; em_n = em_p;
    tg_c = tg_n; tg_n = tg_p;
  }

  // readout: logZ = logacc + log(sum_j a[j] * exp(end[j]))
  float z = 0.f;
  if (act) {
    float ez = __expf(endt[lane]);
    if (pass && ec[lane]) ez = 0.f;
    z = cur[lane] * ez;
  }
#pragma unroll
  for (int off = 32; off; off >>= 1) z += __shfl_xor(z, off, 64);
  const float logZ = logacc + __logf(z);
  if (lane == 0) atomicAdd(out + b, pass ? -logZ : logZ);
}

// ---------------------------------------------------------------------------
extern "C" void kernel_launch(void* const* d_in, const int* in_sizes, int n_in,
                              void* d_out, int out_size, void* d_ws,
                              size_t ws_size, hipStream_t stream) {
  (void)in_sizes; (void)n_in; (void)out_size; (void)ws_size;
  const float* feats = (const float*)d_in[0];
  const int* tags = (const int*)d_in[1];
  const int* lens = (const int*)d_in[2];
  const float* W = (const float*)d_in[3];
  const float* bias = (const float*)d_in[4];
  const float* begin = (const float*)d_in[5];
  const float* trans = (const float*)d_in[6];
  const float* endt = (const float*)d_in[7];
  const int* bc = (const int*)d_in[8];
  const int* ec = (const int*)d_in[9];
  const int* tc = (const int*)d_in[10];

  float* em = (float*)d_ws;  // T*B*L floats = 6 MB scratch
  float* out = (float*)d_out;

  hipMemsetAsync(d_out, 0, B_ * sizeof(float), stream);

  emis_gemm<<<dim3(TB_ / 128), dim3(256), 0, stream>>>(feats, W, bias, em);
  crf_scan<<<dim3(2 * B_), dim3(64), 0, stream>>>(em, tags, lens, begin, trans,
                                                  endt, bc, ec, tc, out);
}

// Round 2
// 454.659 us; speedup vs baseline: 1.5892x; 1.5892x over previous
//
#include <hip/hip_runtime.h>

// Problem constants (from reference): T=1024, B=32, D=768, L=48
#define T_ 1024
#define B_ 32
#define D_ 768
#define L_ 48
#define TB_ (T_ * B_)   // 32768 rows of the emissions GEMM

// ---------------------------------------------------------------------------
// Kernel A: E = exp(feats @ W + b)   (fp32, M=32768 N=48 K=768)
// block = 256 threads, tile = 128 rows x 48 cols, K-chunks of 64.
// Thread microtile = 4 rows x 6 cols. Register-prefetch double buffering:
// next chunk's global loads are issued right after the barrier and land in
// registers while the current chunk computes (overlaps HBM latency).
// #pragma unroll 4 on the k4 loop to bound VGPR pressure (spill suspicion).
// ---------------------------------------------------------------------------
__global__ __launch_bounds__(256) void emis_gemm(
    const float* __restrict__ feats, const float* __restrict__ W,
    const float* __restrict__ bias, float* __restrict__ E) {
  __shared__ float fbuf[128 * 68];
  __shared__ float wbuf[48 * 68];
  const int tid = threadIdx.x;
  const int cg = tid & 7;    // col group 0..7  -> cols c0..c0+5
  const int rg = tid >> 3;   // row group 0..31 -> rows r0..r0+3
  const int c0 = cg * 6;
  const int r0 = rg * 4;
  const int rowbase = blockIdx.x * 128;

  float acc[4][6];
#pragma unroll
  for (int i = 0; i < 4; i++)
#pragma unroll
    for (int c = 0; c < 6; c++) acc[i][c] = 0.f;

  float4 freg[8];
  float wreg[12];

  // load chunk kc of feats/W into registers (coalesced float4 for feats)
  auto load_chunk = [&](int kc) {
#pragma unroll
    for (int i = 0; i < 8; i++) {
      int flat = i * 1024 + tid * 4;  // 0..8191
      int r = flat >> 6;
      int kp = flat & 63;
      freg[i] = *(const float4*)(feats + (size_t)(rowbase + r) * D_ + kc + kp);
    }
#pragma unroll
    for (int i = 0; i < 12; i++) {
      int idx = tid + i * 256;   // 0..3071
      int ko = idx / 48;
      int j = idx - ko * 48;
      wreg[i] = W[(kc + ko) * L_ + j];
    }
  };
  auto store_chunk = [&]() {
#pragma unroll
    for (int i = 0; i < 8; i++) {
      int flat = i * 1024 + tid * 4;
      int r = flat >> 6;
      int kp = flat & 63;
      *(float4*)(fbuf + r * 68 + kp) = freg[i];
    }
#pragma unroll
    for (int i = 0; i < 12; i++) {
      int idx = tid + i * 256;
      int ko = idx / 48;
      int j = idx - ko * 48;
      wbuf[j * 68 + ko] = wreg[i];  // transposed: wbuf[j][ko]
    }
  };

  load_chunk(0);
  for (int kc = 0; kc < D_; kc += 64) {
    __syncthreads();  // prev compute done before overwrite
    store_chunk();
    __syncthreads();
    if (kc + 64 < D_) load_chunk(kc + 64);  // issue early; lands during compute
#pragma unroll 4
    for (int k4 = 0; k4 < 16; k4++) {
      float4 fv[4];
      float4 wv[6];
#pragma unroll
      for (int i = 0; i < 4; i++)
        fv[i] = *(const float4*)(fbuf + (r0 + i) * 68 + k4 * 4);
#pragma unroll
      for (int c = 0; c < 6; c++)
        wv[c] = *(const float4*)(wbuf + (c0 + c) * 68 + k4 * 4);
#pragma unroll
      for (int i = 0; i < 4; i++) {
#pragma unroll
        for (int c = 0; c < 6; c++) {
          acc[i][c] = fmaf(fv[i].x, wv[c].x, acc[i][c]);
          acc[i][c] = fmaf(fv[i].y, wv[c].y, acc[i][c]);
          acc[i][c] = fmaf(fv[i].z, wv[c].z, acc[i][c]);
          acc[i][c] = fmaf(fv[i].w, wv[c].w, acc[i][c]);
        }
      }
    }
  }
#pragma unroll
  for (int i = 0; i < 4; i++)
#pragma unroll
    for (int c = 0; c < 6; c++)
      E[(size_t)(rowbase + r0 + i) * L_ + c0 + c] =
          __expf(acc[i][c] + bias[c0 + c]);
}

// ---------------------------------------------------------------------------
// Kernel B: CRF forward scans in scaled probability space, readlane matvec.
// grid = 64 (2 passes x 32 batches), block = 1 wave.
// Lane j owns state a[j] and P row P[k]=exp(trans[j][k]) (0 if constrained).
// Per step: u[j] = (sum_k readlane(a,k)*P[k]) * E[t,b,j], tag-masked for
// pass 1. Pure VALU: 48 v_readlane + 48 v_fmac, no LDS, no barrier.
// Emissions/tags batched 8 steps ahead into registers (latency hidden).
// Rescale by wave-max every 8 steps, accumulating log(m).
// ---------------------------------------------------------------------------
__global__ __launch_bounds__(64) void crf_scan(
    const float* __restrict__ E, const int* __restrict__ tags,
    const int* __restrict__ lens, const float* __restrict__ begin,
    const float* __restrict__ trans, const float* __restrict__ endt,
    const int* __restrict__ bc, const int* __restrict__ ec,
    const int* __restrict__ tc, float* __restrict__ out) {
  const int s = blockIdx.x;
  const int pass = s & 1;   // 0 = unconstrained fwd, 1 = constrained partial
  const int b = s >> 1;
  const int lane = threadIdx.x;
  const bool act = lane < L_;
  const int len = lens[b];            // in [512, 1024]
  const int stride = B_ * L_;
  const int base = b * L_ + (act ? lane : 0);  // clamped for lanes 48..63

  // Transition row in registers; 0 for inactive lanes and constrained entries
  float P[L_];
#pragma unroll
  for (int k = 0; k < L_; k++) P[k] = 0.f;
  if (act) {
#pragma unroll
    for (int k = 0; k < L_; k++) {
      float p = __expf(trans[lane * L_ + k]);
      if (pass && tc[lane * L_ + k]) p = 0.f;
      P[k] = p;
    }
  }

  // init state: a0 = E[0]*exp(begin), masked for pass 1
  float a = 0.f;
  if (act) {
    a = E[base] * __expf(begin[lane]);
    if (pass && (bc[lane] || tags[base])) a = 0.f;
  }
  float logacc = 0.f;

  // one step of the recurrence; rescale==true at absolute t % 8 == 0
  auto step = [&](float ev, int tg, bool rescale) {
    float s0 = 0.f, s1 = 0.f, s2 = 0.f, s3 = 0.f;
#pragma unroll
    for (int k = 0; k < L_; k += 4) {
      s0 = fmaf(__int_as_float(__builtin_amdgcn_readlane(__float_as_int(a), k + 0)), P[k + 0], s0);
      s1 = fmaf(__int_as_float(__builtin_amdgcn_readlane(__float_as_int(a), k + 1)), P[k + 1], s1);
      s2 = fmaf(__int_as_float(__builtin_amdgcn_readlane(__float_as_int(a), k + 2)), P[k + 2], s2);
      s3 = fmaf(__int_as_float(__builtin_amdgcn_readlane(__float_as_int(a), k + 3)), P[k + 3], s3);
    }
    float u = ((s0 + s1) + (s2 + s3)) * ev;
    if (pass && tg) u = 0.f;
    if (rescale) {
      float m = u;
#pragma unroll
      for (int off = 32; off; off >>= 1) m = fmaxf(m, __shfl_xor(m, off, 64));
      m = fmaxf(m, 1e-30f);
      u = u / m;
      logacc += __logf(m);
    }
    a = u;
  };

  // preload emissions/tags for t = 1..8
  float e8[8];
  int tg8[8];
#pragma unroll
  for (int i = 0; i < 8; i++) {
    int tt = 1 + i;                      // len >= 512, always valid
    e8[i] = E[tt * stride + base];
    tg8[i] = pass ? tags[tt * stride + base] : 0;
  }

  int t = 1;  // t stays == 1 (mod 8); rescale lands at unrolled i == 7
  for (; t + 8 <= len; t += 8) {
    float p8[8];
    int q8[8];
#pragma unroll
    for (int i = 0; i < 8; i++) {
      int tt = t + 8 + i;
      tt = (tt < len) ? tt : (len - 1);
      p8[i] = E[tt * stride + base];
      q8[i] = pass ? tags[tt * stride + base] : 0;
    }
#pragma unroll
    for (int i = 0; i < 8; i++) step(e8[i], tg8[i], i == 7);
#pragma unroll
    for (int i = 0; i < 8; i++) { e8[i] = p8[i]; tg8[i] = q8[i]; }
  }
  // tail: at most 7 steps, e8 already holds times t..t+7 (clamped)
#pragma unroll
  for (int i = 0; i < 8; i++) {
    if (t + i < len) step(e8[i], tg8[i], false);
  }

  // readout: logZ = logacc + log(sum_j a[j]*exp(end[j]))
  float z = 0.f;
  if (act) {
    float ez = __expf(endt[lane]);
    if (pass && ec[lane]) ez = 0.f;
    z = a * ez;
  }
#pragma unroll
  for (int off = 32; off; off >>= 1) z += __shfl_xor(z, off, 64);
  const float logZ = logacc + __logf(z);
  if (lane == 0) atomicAdd(out + b, pass ? -logZ : logZ);
}

// ---------------------------------------------------------------------------
extern "C" void kernel_launch(void* const* d_in, const int* in_sizes, int n_in,
                              void* d_out, int out_size, void* d_ws,
                              size_t ws_size, hipStream_t stream) {
  (void)in_sizes; (void)n_in; (void)out_size; (void)ws_size;
  const float* feats = (const float*)d_in[0];
  const int* tags = (const int*)d_in[1];
  const int* lens = (const int*)d_in[2];
  const float* W = (const float*)d_in[3];
  const float* bias = (const float*)d_in[4];
  const float* begin = (const float*)d_in[5];
  const float* trans = (const float*)d_in[6];
  const float* endt = (const float*)d_in[7];
  const int* bc = (const int*)d_in[8];
  const int* ec = (const int*)d_in[9];
  const int* tc = (const int*)d_in[10];

  float* E = (float*)d_ws;  // T*B*L floats = 6 MB scratch, exp(emissions)
  float* out = (float*)d_out;

  hipMemsetAsync(d_out, 0, B_ * sizeof(float), stream);

  emis_gemm<<<dim3(TB_ / 128), dim3(256), 0, stream>>>(feats, W, bias, E);
  crf_scan<<<dim3(2 * B_), dim3(64), 0, stream>>>(E, tags, lens, begin, trans,
                                                  endt, bc, ec, tc, out);
}

// Round 3
// 446.784 us; speedup vs baseline: 1.6172x; 1.0176x over previous
//
#include <hip/hip_runtime.h>

// Problem constants (from reference): T=1024, B=32, D=768, L=48
#define T_ 1024
#define B_ 32
#define D_ 768
#define L_ 48
#define TB_ (T_ * B_)   // 32768 rows of the emissions GEMM

// ---------------------------------------------------------------------------
// Kernel A: E = exp(feats @ W + b)   (fp32, M=32768 N=48 K=768)
// block = 256 threads (4 waves), tile = 128 rows x 48 cols, K-chunks of 64.
// feats staged via global_load_lds (width 16, no VGPR round-trip) into an
// UNPADDED 128x64 LDS buffer with XOR swizzle: slot chunk = gchunk ^ (row&7).
// Microtile = rows {rg, rg+32, rg+64, rg+96} x 6 cols: per-wave row groups
// rg&7 = 0..7 -> swizzled reads hit all 8 bank groups (conflict-free).
// W staged through VGPRs into wbuf padded 68 (2-way max = free).
// ---------------------------------------------------------------------------
__global__ __launch_bounds__(256) void emis_gemm(
    const float* __restrict__ feats, const float* __restrict__ W,
    const float* __restrict__ bias, float* __restrict__ E) {
  __shared__ float fbuf[128 * 64];   // row-major, 16 chunks of 16B per row
  __shared__ float wbuf[48 * 68];    // wbuf[j][ko], padded
  const int tid = threadIdx.x;
  const int wv = tid >> 6;           // wave id 0..3
  const int lane = tid & 63;
  const int cg = tid & 7;            // col group -> cols c0..c0+5
  const int rg = tid >> 3;           // row group 0..31 -> rows rg+32i
  const int c0 = cg * 6;
  const int rowbase = blockIdx.x * 128;
  const int r7 = rg & 7;

  float acc[4][6];
#pragma unroll
  for (int i = 0; i < 4; i++)
#pragma unroll
    for (int c = 0; c < 6; c++) acc[i][c] = 0.f;

  for (int kc = 0; kc < D_; kc += 64) {
    __syncthreads();  // previous chunk's reads complete before overwrite

    // feats chunk: 8 global_load_lds per wave, 4 rows (64 slots) each.
    // lane -> row = rowstart + lane/16, slot = lane%16; global chunk is
    // slot ^ (row&7) so LDS slot (r, s) holds global chunk (s ^ (r&7)).
#pragma unroll
    for (int inst = 0; inst < 8; inst++) {
      const int rowstart = wv * 32 + inst * 4;
      const int r = rowstart + (lane >> 4);
      const int slot = lane & 15;
      const int gch = slot ^ (r & 7);
      const float* g = feats + (size_t)(rowbase + r) * D_ + kc + gch * 4;
      float* l = fbuf + rowstart * 64;  // wave-uniform base; +lane*16B implied
      __builtin_amdgcn_global_load_lds(
          (const __attribute__((address_space(1))) uint32_t*)g,
          (__attribute__((address_space(3))) uint32_t*)l, 16, 0, 0);
    }

    // W chunk transposed: wbuf[j][ko] = W[kc+ko][j]
#pragma unroll
    for (int i = 0; i < 12; i++) {
      const int idx = tid + i * 256;  // 0..3071
      const int ko = idx / 48;
      const int j = idx - ko * 48;
      wbuf[j * 68 + ko] = W[(kc + ko) * L_ + j];
    }

    __syncthreads();  // drains vmcnt (global_load_lds) + lgkm (ds_write)

#pragma unroll 4
    for (int k4 = 0; k4 < 16; k4++) {
      float4 fv[4];
      float4 wv4[6];
      const int sch = (k4 ^ r7) << 2;  // swizzled chunk offset (floats)
#pragma unroll
      for (int i = 0; i < 4; i++)
        fv[i] = *(const float4*)(fbuf + (rg + 32 * i) * 64 + sch);
#pragma unroll
      for (int c = 0; c < 6; c++)
        wv4[c] = *(const float4*)(wbuf + (c0 + c) * 68 + k4 * 4);
#pragma unroll
      for (int i = 0; i < 4; i++) {
#pragma unroll
        for (int c = 0; c < 6; c++) {
          acc[i][c] = fmaf(fv[i].x, wv4[c].x, acc[i][c]);
          acc[i][c] = fmaf(fv[i].y, wv4[c].y, acc[i][c]);
          acc[i][c] = fmaf(fv[i].z, wv4[c].z, acc[i][c]);
          acc[i][c] = fmaf(fv[i].w, wv4[c].w, acc[i][c]);
        }
      }
    }
  }

  // epilogue: E = exp(acc + bias), rows rg+32i, cols c0..c0+5 (float2 x3)
#pragma unroll
  for (int i = 0; i < 4; i++) {
    float* dst = E + (size_t)(rowbase + rg + 32 * i) * L_ + c0;
#pragma unroll
    for (int c = 0; c < 6; c += 2) {
      float2 v;
      v.x = __expf(acc[i][c + 0] + bias[c0 + c + 0]);
      v.y = __expf(acc[i][c + 1] + bias[c0 + c + 1]);
      *(float2*)(dst + c) = v;
    }
  }
}

// ---------------------------------------------------------------------------
// Kernel B: CRF forward scans in scaled probability space, readlane matvec.
// grid = 64 (2 passes x 32 batches), block = 1 wave.
// Lane j owns state a[j] and P row P[k]=exp(trans[j][k]) (0 if constrained).
// Per step: batch ALL 48 readlanes into uniform (SGPR) array first, THEN the
// 48 fmas — avoids the per-pair VALU->SGPR->VALU hazard wait-states.
// Emissions/tags batched 8 steps ahead; rescale by wave-max every 8 steps.
// ---------------------------------------------------------------------------
__global__ __launch_bounds__(64) void crf_scan(
    const float* __restrict__ E, const int* __restrict__ tags,
    const int* __restrict__ lens, const float* __restrict__ begin,
    const float* __restrict__ trans, const float* __restrict__ endt,
    const int* __restrict__ bc, const int* __restrict__ ec,
    const int* __restrict__ tc, float* __restrict__ out) {
  const int s = blockIdx.x;
  const int pass = s & 1;   // 0 = unconstrained fwd, 1 = constrained partial
  const int b = s >> 1;
  const int lane = threadIdx.x;
  const bool act = lane < L_;
  const int len = lens[b];            // in [512, 1024]
  const int stride = B_ * L_;
  const int base = b * L_ + (act ? lane : 0);  // clamped for lanes 48..63

  // Transition row in registers; 0 for inactive lanes and constrained entries
  float P[L_];
#pragma unroll
  for (int k = 0; k < L_; k++) P[k] = 0.f;
  if (act) {
#pragma unroll
    for (int k = 0; k < L_; k++) {
      float p = __expf(trans[lane * L_ + k]);
      if (pass && tc[lane * L_ + k]) p = 0.f;
      P[k] = p;
    }
  }

  // init state: a0 = E[0]*exp(begin), masked for pass 1
  float a = 0.f;
  if (act) {
    a = E[base] * __expf(begin[lane]);
    if (pass && (bc[lane] || tags[base])) a = 0.f;
  }
  float logacc = 0.f;

  auto step = [&](float ev, int tg, bool rescale) {
    // phase 1: broadcast the whole state into uniform regs (SGPRs)
    const int ai = __float_as_int(a);
    int sa[L_];
#pragma unroll
    for (int k = 0; k < L_; k++) sa[k] = __builtin_amdgcn_readlane(ai, k);
    // phase 2: the matvec, 4 independent chains
    float s0 = 0.f, s1 = 0.f, s2 = 0.f, s3 = 0.f;
#pragma unroll
    for (int k = 0; k < L_; k += 4) {
      s0 = fmaf(__int_as_float(sa[k + 0]), P[k + 0], s0);
      s1 = fmaf(__int_as_float(sa[k + 1]), P[k + 1], s1);
      s2 = fmaf(__int_as_float(sa[k + 2]), P[k + 2], s2);
      s3 = fmaf(__int_as_float(sa[k + 3]), P[k + 3], s3);
    }
    float u = ((s0 + s1) + (s2 + s3)) * ev;
    if (pass && tg) u = 0.f;
    if (rescale) {
      float m = u;
#pragma unroll
      for (int off = 32; off; off >>= 1) m = fmaxf(m, __shfl_xor(m, off, 64));
      m = fmaxf(m, 1e-30f);
      u = u / m;
      logacc += __logf(m);
    }
    a = u;
  };

  // preload emissions/tags for t = 1..8 (len >= 512 so always valid)
  float e8[8];
  int tg8[8];
#pragma unroll
  for (int i = 0; i < 8; i++) {
    e8[i] = E[(1 + i) * stride + base];
    tg8[i] = pass ? tags[(1 + i) * stride + base] : 0;
  }

  int t = 1;  // t stays == 1 (mod 8); rescale lands at unrolled i == 7
  for (; t + 8 <= len; t += 8) {
    float p8[8];
    int q8[8];
#pragma unroll
    for (int i = 0; i < 8; i++) {
      int tt = t + 8 + i;
      tt = (tt < len) ? tt : (len - 1);
      p8[i] = E[tt * stride + base];
      q8[i] = pass ? tags[tt * stride + base] : 0;
    }
#pragma unroll
    for (int i = 0; i < 8; i++) step(e8[i], tg8[i], i == 7);
#pragma unroll
    for (int i = 0; i < 8; i++) { e8[i] = p8[i]; tg8[i] = q8[i]; }
  }
  // tail: at most 7 steps, e8 already holds times t..t+7 (clamped)
#pragma unroll
  for (int i = 0; i < 8; i++) {
    if (t + i < len) step(e8[i], tg8[i], false);
  }

  // readout: logZ = logacc + log(sum_j a[j]*exp(end[j]))
  float z = 0.f;
  if (act) {
    float ez = __expf(endt[lane]);
    if (pass && ec[lane]) ez = 0.f;
    z = a * ez;
  }
#pragma unroll
  for (int off = 32; off; off >>= 1) z += __shfl_xor(z, off, 64);
  const float logZ = logacc + __logf(z);
  if (lane == 0) atomicAdd(out + b, pass ? -logZ : logZ);
}

// ---------------------------------------------------------------------------
extern "C" void kernel_launch(void* const* d_in, const int* in_sizes, int n_in,
                              void* d_out, int out_size, void* d_ws,
                              size_t ws_size, hipStream_t stream) {
  (void)in_sizes; (void)n_in; (void)out_size; (void)ws_size;
  const float* feats = (const float*)d_in[0];
  const int* tags = (const int*)d_in[1];
  const int* lens = (const int*)d_in[2];
  const float* W = (const float*)d_in[3];
  const float* bias = (const float*)d_in[4];
  const float* begin = (const float*)d_in[5];
  const float* trans = (const float*)d_in[6];
  const float* endt = (const float*)d_in[7];
  const int* bc = (const int*)d_in[8];
  const int* ec = (const int*)d_in[9];
  const int* tc = (const int*)d_in[10];

  float* E = (float*)d_ws;  // T*B*L floats = 6 MB scratch, exp(emissions)
  float* out = (float*)d_out;

  hipMemsetAsync(d_out, 0, B_ * sizeof(float), stream);

  emis_gemm<<<dim3(TB_ / 128), dim3(256), 0, stream>>>(feats, W, bias, E);
  crf_scan<<<dim3(2 * B_), dim3(64), 0, stream>>>(E, tags, lens, begin, trans,
                                                  endt, bc, ec, tc, out);
}